// Round 1
// baseline (4222.549 us; speedup 1.0000x reference)
//
#include <hip/hip_runtime.h>
#include <math.h>

#define N_NODES 262144
#define N_EDGES 4194304
#define N_GRAPHS 1024

// ---------------------------------------------------------------------------
// Kernel A: per-edge message MLP + scatter-add into per-node accumulators.
//   m_in = [x[dst](4), x[src](4), dist(1)]  -> h1 = silu(m_in@W1+b1)
//   msg  = h1@W2+b2  -> atomicAdd into aggsum[dst], cnt[dst] += 1
// Weights staged in LDS (uniform broadcast reads, conflict-free).
// ---------------------------------------------------------------------------
__global__ __launch_bounds__(256) void edge_kernel(
    const float* __restrict__ x, const float* __restrict__ pos,
    const float* __restrict__ W1, const float* __restrict__ b1,
    const float* __restrict__ W2, const float* __restrict__ b2,
    const int* __restrict__ ei,
    float* __restrict__ aggsum, float* __restrict__ cnt)
{
    __shared__ float sW1[144], sb1[16], sW2[256], sb2[16];
    for (int i = threadIdx.x; i < 144; i += blockDim.x) sW1[i] = W1[i];
    for (int i = threadIdx.x; i < 256; i += blockDim.x) sW2[i] = W2[i];
    if (threadIdx.x < 16) { sb1[threadIdx.x] = b1[threadIdx.x]; sb2[threadIdx.x] = b2[threadIdx.x]; }
    __syncthreads();

    int stride = gridDim.x * blockDim.x;
    for (int e = blockIdx.x * blockDim.x + threadIdx.x; e < N_EDGES; e += stride) {
        int s = ei[e];             // source (x_j)
        int d = ei[N_EDGES + e];   // target (x_i) — aggregation index

        float4 xd = ((const float4*)x)[d];
        float4 xs = ((const float4*)x)[s];
        float dx = pos[3*s+0] - pos[3*d+0];
        float dy = pos[3*s+1] - pos[3*d+1];
        float dz = pos[3*s+2] - pos[3*d+2];
        float dist = sqrtf(dx*dx + dy*dy + dz*dz);

        float m[9] = {xd.x, xd.y, xd.z, xd.w, xs.x, xs.y, xs.z, xs.w, dist};

        float h1[16];
        #pragma unroll
        for (int j = 0; j < 16; ++j) {
            float a = sb1[j];
            #pragma unroll
            for (int i = 0; i < 9; ++i) a = fmaf(m[i], sW1[i*16 + j], a);
            // silu
            h1[j] = a / (1.0f + __expf(-a));
        }

        float* dstp = aggsum + (size_t)d * 16;
        #pragma unroll
        for (int j = 0; j < 16; ++j) {
            float a = sb2[j];
            #pragma unroll
            for (int i = 0; i < 16; ++i) a = fmaf(h1[i], sW2[i*16 + j], a);
            atomicAdd(dstp + j, a);
        }
        atomicAdd(cnt + d, 1.0f);
    }
}

// ---------------------------------------------------------------------------
// Kernel B: per-node finalize: mean, relu, softmax gate s, write s, and
// atomicAdd s[k]*h[d] into pooled[batch[n]].
// ---------------------------------------------------------------------------
__global__ __launch_bounds__(256) void node_kernel(
    const float* __restrict__ aggsum, const float* __restrict__ cnt,
    const float* __restrict__ Wp, const float* __restrict__ bp,
    const int* __restrict__ batch,
    float* __restrict__ out_s, float* __restrict__ pooled)
{
    int stride = gridDim.x * blockDim.x;
    for (int n = blockIdx.x * blockDim.x + threadIdx.x; n < N_NODES; n += stride) {
        float c = cnt[n];
        float inv = 1.0f / fmaxf(c, 1.0f);

        float h[16];
        const float4* ap = (const float4*)(aggsum + (size_t)n * 16);
        #pragma unroll
        for (int q = 0; q < 4; ++q) {
            float4 v = ap[q];
            h[4*q+0] = fmaxf(v.x * inv, 0.0f);
            h[4*q+1] = fmaxf(v.y * inv, 0.0f);
            h[4*q+2] = fmaxf(v.z * inv, 0.0f);
            h[4*q+3] = fmaxf(v.w * inv, 0.0f);
        }

        float l0 = bp[0], l1 = bp[1];
        #pragma unroll
        for (int j = 0; j < 16; ++j) {
            l0 = fmaf(h[j], Wp[2*j + 0], l0);
            l1 = fmaf(h[j], Wp[2*j + 1], l1);
        }
        float mx = fmaxf(l0, l1);
        float e0 = __expf(l0 - mx), e1 = __expf(l1 - mx);
        float is = 1.0f / (e0 + e1);
        float s0 = e0 * is, s1 = e1 * is;

        out_s[2*n + 0] = s0;
        out_s[2*n + 1] = s1;

        float* pp = pooled + (size_t)batch[n] * 32;
        #pragma unroll
        for (int j = 0; j < 16; ++j) {
            atomicAdd(pp + j,      s0 * h[j]);
            atomicAdd(pp + 16 + j, s1 * h[j]);
        }
    }
}

// ---------------------------------------------------------------------------
// Kernel C: z = pooled.reshape(G,32) @ Wz + bz   (1024 x 8 outputs)
// ---------------------------------------------------------------------------
__global__ __launch_bounds__(256) void graph_kernel(
    const float* __restrict__ pooled,
    const float* __restrict__ Wz, const float* __restrict__ bz,
    float* __restrict__ out_z)
{
    int idx = blockIdx.x * blockDim.x + threadIdx.x;
    if (idx >= N_GRAPHS * 8) return;
    int g = idx >> 3, o = idx & 7;
    float a = bz[o];
    const float* pp = pooled + (size_t)g * 32;
    #pragma unroll
    for (int j = 0; j < 32; ++j) a = fmaf(pp[j], Wz[j*8 + o], a);
    out_z[idx] = a;
}

extern "C" void kernel_launch(void* const* d_in, const int* in_sizes, int n_in,
                              void* d_out, int out_size, void* d_ws, size_t ws_size,
                              hipStream_t stream) {
    const float* x    = (const float*)d_in[0];
    const float* pos  = (const float*)d_in[1];
    const float* W1   = (const float*)d_in[2];
    const float* b1   = (const float*)d_in[3];
    const float* W2   = (const float*)d_in[4];
    const float* b2   = (const float*)d_in[5];
    const float* Wp   = (const float*)d_in[6];
    const float* bp   = (const float*)d_in[7];
    const float* Wz   = (const float*)d_in[8];
    const float* bz   = (const float*)d_in[9];
    const int*   ei   = (const int*)d_in[10];
    const int*   batch= (const int*)d_in[11];
    float* out = (float*)d_out;

    // workspace layout (floats): aggsum[N*16] | cnt[N] | pooled[G*32]
    float* aggsum = (float*)d_ws;
    float* cnt    = aggsum + (size_t)N_NODES * 16;
    float* pooled = cnt + N_NODES;
    size_t zero_bytes = ((size_t)N_NODES * 16 + N_NODES + N_GRAPHS * 32) * sizeof(float);
    hipMemsetAsync(d_ws, 0, zero_bytes, stream);

    edge_kernel<<<N_EDGES / 256, 256, 0, stream>>>(x, pos, W1, b1, W2, b2, ei, aggsum, cnt);
    node_kernel<<<N_NODES / 256, 256, 0, stream>>>(aggsum, cnt, Wp, bp, batch,
                                                   out + N_GRAPHS * 8, pooled);
    graph_kernel<<<(N_GRAPHS * 8 + 255) / 256, 256, 0, stream>>>(pooled, Wz, bz, out);
}

// Round 3
// 1060.394 us; speedup vs baseline: 3.9821x; 3.9821x over previous
//
#include <hip/hip_runtime.h>
#include <math.h>

#define N_NODES 262144
#define N_EDGES 4194304
#define N_GRAPHS 1024

// ---------------------------------------------------------------------------
// 1) deg[d] histogram (int atomics, no return value)
// ---------------------------------------------------------------------------
__global__ __launch_bounds__(256) void hist_kernel(const int* __restrict__ ei,
                                                   int* __restrict__ deg) {
    int e = blockIdx.x * 256 + threadIdx.x;
    atomicAdd(&deg[ei[N_EDGES + e]], 1);
}

// ---------------------------------------------------------------------------
// 2) exclusive scan of deg[262144] -> start, cursor  (3 small kernels)
// ---------------------------------------------------------------------------
__global__ __launch_bounds__(256) void scan1(const int* __restrict__ deg,
                                             int* __restrict__ bsum) {
    __shared__ int lsum[256];
    int b = blockIdx.x, t = threadIdx.x;
    int4 v = ((const int4*)deg)[b * 256 + t];
    lsum[t] = v.x + v.y + v.z + v.w;
    __syncthreads();
    for (int o = 128; o > 0; o >>= 1) {
        if (t < o) lsum[t] += lsum[t + o];
        __syncthreads();
    }
    if (t == 0) bsum[b] = lsum[0];
}

__global__ __launch_bounds__(256) void scan2(const int* __restrict__ bsum,
                                             int* __restrict__ boffs) {
    __shared__ int tmp[256];
    int t = threadIdx.x;
    tmp[t] = bsum[t];
    __syncthreads();
    for (int o = 1; o < 256; o <<= 1) {
        int v = (t >= o) ? tmp[t - o] : 0;
        __syncthreads();
        tmp[t] += v;
        __syncthreads();
    }
    boffs[t] = tmp[t] - bsum[t];  // exclusive
}

__global__ __launch_bounds__(256) void scan3(const int* __restrict__ deg,
                                             const int* __restrict__ boffs,
                                             int* __restrict__ start,
                                             int* __restrict__ cursor) {
    __shared__ int tsum[256];
    int b = blockIdx.x, t = threadIdx.x;
    int4 v = ((const int4*)deg)[b * 256 + t];
    int tot = v.x + v.y + v.z + v.w;
    tsum[t] = tot;
    __syncthreads();
    for (int o = 1; o < 256; o <<= 1) {
        int u = (t >= o) ? tsum[t - o] : 0;
        __syncthreads();
        tsum[t] += u;
        __syncthreads();
    }
    int base = boffs[b] + tsum[t] - tot;
    int i = b * 1024 + t * 4;
    int4 p;
    p.x = base;
    p.y = p.x + v.x;
    p.z = p.y + v.y;
    p.w = p.z + v.z;
    ((int4*)start)[i >> 2]  = p;
    ((int4*)cursor)[i >> 2] = p;
}

// ---------------------------------------------------------------------------
// 3) scatter src ids into CSR order (4B/edge instead of 64B msg + RMW lines)
// ---------------------------------------------------------------------------
__global__ __launch_bounds__(256) void scatter_kernel(const int* __restrict__ ei,
                                                      int* __restrict__ cursor,
                                                      int* __restrict__ srcs) {
    int e = blockIdx.x * 256 + threadIdx.x;
    int s = ei[e];
    int d = ei[N_EDGES + e];
    int slot = atomicAdd(&cursor[d], 1);
    srcs[slot] = s;
}

// ---------------------------------------------------------------------------
// 4) gather + edge MLP + mean + relu + softmax gate.
//    16 lanes per node; each lane computes full MLP for its strided edges,
//    accumulates msg[16]; 4-step shfl_xor reduce-scatter leaves component g
//    on lane g. No atomics, no LDS data traffic (weights broadcast only).
// ---------------------------------------------------------------------------
__global__ __launch_bounds__(256) void node_gather_kernel(
    const float* __restrict__ x, const float* __restrict__ pos,
    const int* __restrict__ srcs, const int* __restrict__ start,
    const int* __restrict__ deg,
    const float* __restrict__ W1, const float* __restrict__ b1,
    const float* __restrict__ W2, const float* __restrict__ b2,
    const float* __restrict__ Wp, const float* __restrict__ bp,
    float* __restrict__ out_s, float* __restrict__ h_out)
{
    __shared__ float sW1[144], sb1[16], sW2[256], sb2[16], sWp[32], sbp[2];
    for (int i = threadIdx.x; i < 144; i += 256) sW1[i] = W1[i];
    for (int i = threadIdx.x; i < 256; i += 256) sW2[i] = W2[i];
    if (threadIdx.x < 16) { sb1[threadIdx.x] = b1[threadIdx.x]; sb2[threadIdx.x] = b2[threadIdx.x]; }
    if (threadIdx.x < 32) sWp[threadIdx.x] = Wp[threadIdx.x];
    if (threadIdx.x < 2)  sbp[threadIdx.x] = bp[threadIdx.x];
    __syncthreads();

    int t = threadIdx.x;
    int g = t & 15;            // lane within 16-lane node group
    int n = blockIdx.x * 16 + (t >> 4);   // 16 nodes per block -> grid N_NODES/16

    int s0i = start[n];
    int dg  = deg[n];

    float4 xn = ((const float4*)x)[n];
    float pnx = pos[3 * n], pny = pos[3 * n + 1], pnz = pos[3 * n + 2];

    float acc[16];
    #pragma unroll
    for (int c = 0; c < 16; ++c) acc[c] = 0.0f;

    for (int k = g; k < dg; k += 16) {
        int s = srcs[s0i + k];
        float4 xs = ((const float4*)x)[s];
        float dx = pos[3 * s]     - pnx;
        float dy = pos[3 * s + 1] - pny;
        float dz = pos[3 * s + 2] - pnz;
        float dist = sqrtf(dx * dx + dy * dy + dz * dz);

        float m[9] = {xn.x, xn.y, xn.z, xn.w, xs.x, xs.y, xs.z, xs.w, dist};
        float h1[16];
        #pragma unroll
        for (int j = 0; j < 16; ++j) {
            float a = sb1[j];
            #pragma unroll
            for (int i = 0; i < 9; ++i) a = fmaf(m[i], sW1[i * 16 + j], a);
            h1[j] = a / (1.0f + __expf(-a));  // silu
        }
        #pragma unroll
        for (int c = 0; c < 16; ++c) {
            float a = acc[c];
            #pragma unroll
            for (int i = 0; i < 16; ++i) a = fmaf(h1[i], sW2[i * 16 + c], a);
            acc[c] = a;
        }
    }

    // reduce-scatter across the 16-lane group: lane g ends with sum of comp g
    #pragma unroll
    for (int mset = 8; mset > 0; mset >>= 1) {
        #pragma unroll
        for (int c = 0; c < 16; ++c) {
            float tmp = __shfl_xor(acc[c], mset);
            if (((c ^ g) & mset) == 0) acc[c] += tmp;
        }
    }
    float red = acc[0];
    #pragma unroll
    for (int c = 1; c < 16; ++c) red = (g == c) ? acc[c] : red;

    float fdg = (float)dg;
    float inv = 1.0f / fmaxf(fdg, 1.0f);
    float h = fmaxf((red + fdg * sb2[g]) * inv, 0.0f);  // mean(+bias) then relu

    // logits via 16-lane allreduce
    float c0 = h * sWp[2 * g], c1 = h * sWp[2 * g + 1];
    #pragma unroll
    for (int mset = 8; mset > 0; mset >>= 1) {
        c0 += __shfl_xor(c0, mset);
        c1 += __shfl_xor(c1, mset);
    }
    float l0 = c0 + sbp[0], l1 = c1 + sbp[1];
    float mx = fmaxf(l0, l1);
    float e0 = __expf(l0 - mx), e1 = __expf(l1 - mx);
    float isum = 1.0f / (e0 + e1);

    if (g == 0) {
        float2 sv = make_float2(e0 * isum, e1 * isum);
        ((float2*)out_s)[n] = sv;
    }
    h_out[n * 16 + g] = h;
}

// ---------------------------------------------------------------------------
// 5) per-graph pooling + z = pooled @ Wz + bz. One block per graph; node
//    range found by binary search on sorted batch. No atomics.
// ---------------------------------------------------------------------------
__global__ __launch_bounds__(256) void pool_kernel(
    const float* __restrict__ h, const float* __restrict__ s,
    const int* __restrict__ batch,
    const float* __restrict__ Wz, const float* __restrict__ bz,
    float* __restrict__ z)
{
    int gph = blockIdx.x;
    __shared__ int slo, shi;
    if (threadIdx.x == 0) {
        int lo = 0, hi = N_NODES;
        while (lo < hi) { int mid = (lo + hi) >> 1; if (batch[mid] < gph) lo = mid + 1; else hi = mid; }
        slo = lo;
        hi = N_NODES;
        while (lo < hi) { int mid = (lo + hi) >> 1; if (batch[mid] < gph + 1) lo = mid + 1; else hi = mid; }
        shi = lo;
    }
    __syncthreads();

    float p[32];
    #pragma unroll
    for (int c = 0; c < 32; ++c) p[c] = 0.0f;

    for (int n = slo + threadIdx.x; n < shi; n += 256) {
        float2 sv = ((const float2*)s)[n];
        const float4* hp = (const float4*)(h + (size_t)n * 16);
        #pragma unroll
        for (int q = 0; q < 4; ++q) {
            float4 v = hp[q];
            p[4 * q + 0]      = fmaf(sv.x, v.x, p[4 * q + 0]);
            p[4 * q + 1]      = fmaf(sv.x, v.y, p[4 * q + 1]);
            p[4 * q + 2]      = fmaf(sv.x, v.z, p[4 * q + 2]);
            p[4 * q + 3]      = fmaf(sv.x, v.w, p[4 * q + 3]);
            p[16 + 4 * q + 0] = fmaf(sv.y, v.x, p[16 + 4 * q + 0]);
            p[16 + 4 * q + 1] = fmaf(sv.y, v.y, p[16 + 4 * q + 1]);
            p[16 + 4 * q + 2] = fmaf(sv.y, v.z, p[16 + 4 * q + 2]);
            p[16 + 4 * q + 3] = fmaf(sv.y, v.w, p[16 + 4 * q + 3]);
        }
    }

    // wave butterfly reduce, then cross-wave via LDS
    #pragma unroll
    for (int mset = 1; mset < 64; mset <<= 1) {
        #pragma unroll
        for (int c = 0; c < 32; ++c) p[c] += __shfl_xor(p[c], mset);
    }
    __shared__ float wsum[4][32];
    int wid = threadIdx.x >> 6, lane = threadIdx.x & 63;
    if (lane == 0) {
        #pragma unroll
        for (int c = 0; c < 32; ++c) wsum[wid][c] = p[c];
    }
    __syncthreads();
    if (threadIdx.x < 8) {
        int o = threadIdx.x;
        float a = bz[o];
        #pragma unroll
        for (int j = 0; j < 32; ++j) {
            float pj = wsum[0][j] + wsum[1][j] + wsum[2][j] + wsum[3][j];
            a = fmaf(pj, Wz[j * 8 + o], a);
        }
        z[gph * 8 + o] = a;
    }
}

extern "C" void kernel_launch(void* const* d_in, const int* in_sizes, int n_in,
                              void* d_out, int out_size, void* d_ws, size_t ws_size,
                              hipStream_t stream) {
    const float* x    = (const float*)d_in[0];
    const float* pos  = (const float*)d_in[1];
    const float* W1   = (const float*)d_in[2];
    const float* b1   = (const float*)d_in[3];
    const float* W2   = (const float*)d_in[4];
    const float* b2   = (const float*)d_in[5];
    const float* Wp   = (const float*)d_in[6];
    const float* bp   = (const float*)d_in[7];
    const float* Wz   = (const float*)d_in[8];
    const float* bz   = (const float*)d_in[9];
    const int*   ei   = (const int*)d_in[10];
    const int*   batch= (const int*)d_in[11];
    float* out = (float*)d_out;
    float* out_z = out;                       // [1024*8]
    float* out_s = out + N_GRAPHS * 8;        // [262144*2]

    // ws layout (4B units): deg[N] | start[N] | cursor[N] | bsum[256] | boffs[256]
    //                       | pad to 1024 | srcs[E] | h[N*16]      (~37 MB)
    int* deg    = (int*)d_ws;
    int* start  = deg + N_NODES;
    int* cursor = start + N_NODES;
    int* bsum   = cursor + N_NODES;
    int* boffs  = bsum + 256;
    int* srcs   = cursor + N_NODES + 1024;
    float* hbuf = (float*)(srcs + N_EDGES);

    hipMemsetAsync(deg, 0, N_NODES * sizeof(int), stream);

    hist_kernel<<<N_EDGES / 256, 256, 0, stream>>>(ei, deg);
    scan1<<<256, 256, 0, stream>>>(deg, bsum);
    scan2<<<1, 256, 0, stream>>>(bsum, boffs);
    scan3<<<256, 256, 0, stream>>>(deg, boffs, start, cursor);
    scatter_kernel<<<N_EDGES / 256, 256, 0, stream>>>(ei, cursor, srcs);
    node_gather_kernel<<<N_NODES / 16, 256, 0, stream>>>(
        x, pos, srcs, start, deg, W1, b1, W2, b2, Wp, bp, out_s, hbuf);
    pool_kernel<<<N_GRAPHS, 256, 0, stream>>>(hbuf, out_s, batch, Wz, bz, out_z);
}

// Round 4
// 272.992 us; speedup vs baseline: 15.4677x; 3.8843x over previous
//
#include <hip/hip_runtime.h>
#include <math.h>

#define N_NODES 262144
#define N_EDGES 4194304
#define N_GRAPHS 1024
#define NB 1024              // dst buckets (256 nodes each)
#define EPB 16384            // edges per block in passes A/B (256 blocks)

// ---------------------------------------------------------------------------
// Pass A: per-block bucket histogram -> cnt[bucket*256 + block]
// ---------------------------------------------------------------------------
__global__ __launch_bounds__(256) void passA_hist(const int* __restrict__ ei,
                                                  int* __restrict__ cnt) {
    __shared__ int lhist[NB];
    int t = threadIdx.x, b = blockIdx.x;
    #pragma unroll
    for (int k = 0; k < 4; ++k) lhist[t + 256 * k] = 0;
    __syncthreads();
    int base = b * EPB;
    for (int i = 0; i < EPB / 256; ++i) {
        int d = ei[N_EDGES + base + i * 256 + t];
        atomicAdd(&lhist[d >> 8], 1);
    }
    __syncthreads();
    #pragma unroll
    for (int k = 0; k < 4; ++k) {
        int kb = t + 256 * k;
        cnt[kb * 256 + b] = lhist[kb];
    }
}

// ---------------------------------------------------------------------------
// Exclusive scan of cnt[262144] -> offs   (3 kernels, 256x256x int4)
// ---------------------------------------------------------------------------
__global__ __launch_bounds__(256) void scan1(const int* __restrict__ v,
                                             int* __restrict__ bsum) {
    __shared__ int lsum[256];
    int b = blockIdx.x, t = threadIdx.x;
    int4 x = ((const int4*)v)[b * 256 + t];
    lsum[t] = x.x + x.y + x.z + x.w;
    __syncthreads();
    for (int o = 128; o > 0; o >>= 1) {
        if (t < o) lsum[t] += lsum[t + o];
        __syncthreads();
    }
    if (t == 0) bsum[b] = lsum[0];
}

__global__ __launch_bounds__(256) void scan2(const int* __restrict__ bsum,
                                             int* __restrict__ boffs) {
    __shared__ int tmp[256];
    int t = threadIdx.x;
    tmp[t] = bsum[t];
    __syncthreads();
    for (int o = 1; o < 256; o <<= 1) {
        int u = (t >= o) ? tmp[t - o] : 0;
        __syncthreads();
        tmp[t] += u;
        __syncthreads();
    }
    boffs[t] = tmp[t] - bsum[t];
}

__global__ __launch_bounds__(256) void scan3(const int* __restrict__ v,
                                             const int* __restrict__ boffs,
                                             int* __restrict__ offs) {
    __shared__ int tsum[256];
    int b = blockIdx.x, t = threadIdx.x;
    int4 x = ((const int4*)v)[b * 256 + t];
    int tot = x.x + x.y + x.z + x.w;
    tsum[t] = tot;
    __syncthreads();
    for (int o = 1; o < 256; o <<= 1) {
        int u = (t >= o) ? tsum[t - o] : 0;
        __syncthreads();
        tsum[t] += u;
        __syncthreads();
    }
    int base = boffs[b] + tsum[t] - tot;
    int4 p;
    p.x = base;
    p.y = p.x + x.x;
    p.z = p.y + x.y;
    p.w = p.z + x.z;
    ((int4*)offs)[b * 256 + t] = p;
}

// ---------------------------------------------------------------------------
// Pass B: scatter packed (src | dstlow<<18) into bucket-sorted order using
// per-(block,bucket) reserved ranges (LDS cursors seeded from offs).
// ---------------------------------------------------------------------------
__global__ __launch_bounds__(256) void passB_scatter(const int* __restrict__ ei,
                                                     const int* __restrict__ offs,
                                                     int* __restrict__ binned) {
    __shared__ int cur[NB];
    int t = threadIdx.x, b = blockIdx.x;
    #pragma unroll
    for (int k = 0; k < 4; ++k) {
        int kb = t + 256 * k;
        cur[kb] = offs[kb * 256 + b];
    }
    __syncthreads();
    int base = b * EPB;
    for (int i = 0; i < EPB / 256; ++i) {
        int e = base + i * 256 + t;
        int s = ei[e];
        int d = ei[N_EDGES + e];
        int slot = atomicAdd(&cur[d >> 8], 1);
        binned[slot] = s | ((d & 0xFF) << 18);
    }
}

// ---------------------------------------------------------------------------
// Pass C: per-bucket local CSR: node start/deg + srcs in final CSR order.
// All writes land in the bucket's contiguous ~16KB region.
// ---------------------------------------------------------------------------
__global__ __launch_bounds__(256) void passC_csr(const int* __restrict__ binned,
                                                 const int* __restrict__ offs,
                                                 int* __restrict__ startg,
                                                 int* __restrict__ degg,
                                                 int* __restrict__ srcs) {
    __shared__ int ldeg[256], sc[256], lcur[256];
    int t = threadIdx.x, k = blockIdx.x;
    int ebase = offs[k * 256];
    int eend = (k == NB - 1) ? N_EDGES : offs[(k + 1) * 256];
    int ecnt = eend - ebase;

    ldeg[t] = 0;
    __syncthreads();
    for (int i = t; i < ecnt; i += 256) {
        int pk = binned[ebase + i];
        atomicAdd(&ldeg[pk >> 18], 1);
    }
    __syncthreads();
    sc[t] = ldeg[t];
    __syncthreads();
    for (int o = 1; o < 256; o <<= 1) {
        int u = (t >= o) ? sc[t - o] : 0;
        __syncthreads();
        sc[t] += u;
        __syncthreads();
    }
    int excl = sc[t] - ldeg[t];
    int n = k * 256 + t;
    startg[n] = ebase + excl;
    degg[n] = ldeg[t];
    lcur[t] = ebase + excl;
    __syncthreads();
    for (int i = t; i < ecnt; i += 256) {
        int pk = binned[ebase + i];
        int slot = atomicAdd(&lcur[pk >> 18], 1);
        srcs[slot] = pk & 0x3FFFF;
    }
}

// ---------------------------------------------------------------------------
// Pack x(4) + pos(3) into one 32B record per node: 1 cache line per gather.
// ---------------------------------------------------------------------------
__global__ __launch_bounds__(256) void pack_kernel(const float* __restrict__ x,
                                                   const float* __restrict__ pos,
                                                   float4* __restrict__ px) {
    int n = blockIdx.x * 256 + threadIdx.x;
    px[2 * n] = ((const float4*)x)[n];
    px[2 * n + 1] = make_float4(pos[3 * n], pos[3 * n + 1], pos[3 * n + 2], 0.0f);
}

// ---------------------------------------------------------------------------
// Gather + rank-1 edge MLP + mean/relu/softmax + fused per-graph pooling.
// 16 lanes per node; lane g holds W1 col g + W2 row g in registers.
// Each edge is broadcast within the group via 5 shfls; lane g computes h1[g]
// and rank-1-updates acc[c] += h1[g]*W2[g][c]; butterfly reduce-scatter ends
// with component g on lane g. No LDS in the inner loop, no h materialized.
// ---------------------------------------------------------------------------
__global__ __launch_bounds__(256) void node_gather_fused(
    const float4* __restrict__ px,
    const int* __restrict__ srcs, const int* __restrict__ startg,
    const int* __restrict__ degg,
    const float* __restrict__ W1, const float* __restrict__ b1,
    const float* __restrict__ W2, const float* __restrict__ b2,
    const float* __restrict__ Wp, const float* __restrict__ bp,
    const int* __restrict__ batch,
    float* __restrict__ out_s, float* __restrict__ pooled)
{
    int t = threadIdx.x;
    int g = t & 15;
    int n = blockIdx.x * 16 + (t >> 4);

    // per-lane weights (registers, not LDS)
    float w1c[9];
    #pragma unroll
    for (int i = 0; i < 9; ++i) w1c[i] = W1[i * 16 + g];
    float b1g = b1[g], b2g = b2[g];
    float4 w2a = ((const float4*)W2)[g * 4 + 0];
    float4 w2b = ((const float4*)W2)[g * 4 + 1];
    float4 w2c = ((const float4*)W2)[g * 4 + 2];
    float4 w2d = ((const float4*)W2)[g * 4 + 3];
    float wp0 = Wp[2 * g], wp1 = Wp[2 * g + 1];

    int base = startg[n];
    int dg = degg[n];

    float4 xn = px[2 * n];
    float4 pn = px[2 * n + 1];
    float pre = b1g + xn.x * w1c[0] + xn.y * w1c[1] + xn.z * w1c[2] + xn.w * w1c[3];

    float acc[16];
    #pragma unroll
    for (int c = 0; c < 16; ++c) acc[c] = 0.0f;

    for (int k0 = 0; k0 < dg; k0 += 16) {
        int rem = dg - k0;
        int cnt = rem < 16 ? rem : 16;
        float mx0 = 0, mx1 = 0, mx2 = 0, mx3 = 0, md = 0;
        if (g < cnt) {
            int s = srcs[base + k0 + g];
            float4 a = px[2 * s];
            float4 b = px[2 * s + 1];
            mx0 = a.x; mx1 = a.y; mx2 = a.z; mx3 = a.w;
            float dx = b.x - pn.x, dy = b.y - pn.y, dz = b.z - pn.z;
            md = sqrtf(dx * dx + dy * dy + dz * dz);
        }
        for (int j = 0; j < cnt; ++j) {
            float e0 = __shfl(mx0, j, 16);
            float e1 = __shfl(mx1, j, 16);
            float e2 = __shfl(mx2, j, 16);
            float e3 = __shfl(mx3, j, 16);
            float ed = __shfl(md, j, 16);
            float a = pre + e0 * w1c[4] + e1 * w1c[5] + e2 * w1c[6] + e3 * w1c[7] + ed * w1c[8];
            float h1v = a * __builtin_amdgcn_rcpf(1.0f + __expf(-a));  // silu
            acc[0]  = fmaf(h1v, w2a.x, acc[0]);
            acc[1]  = fmaf(h1v, w2a.y, acc[1]);
            acc[2]  = fmaf(h1v, w2a.z, acc[2]);
            acc[3]  = fmaf(h1v, w2a.w, acc[3]);
            acc[4]  = fmaf(h1v, w2b.x, acc[4]);
            acc[5]  = fmaf(h1v, w2b.y, acc[5]);
            acc[6]  = fmaf(h1v, w2b.z, acc[6]);
            acc[7]  = fmaf(h1v, w2b.w, acc[7]);
            acc[8]  = fmaf(h1v, w2c.x, acc[8]);
            acc[9]  = fmaf(h1v, w2c.y, acc[9]);
            acc[10] = fmaf(h1v, w2c.z, acc[10]);
            acc[11] = fmaf(h1v, w2c.w, acc[11]);
            acc[12] = fmaf(h1v, w2d.x, acc[12]);
            acc[13] = fmaf(h1v, w2d.y, acc[13]);
            acc[14] = fmaf(h1v, w2d.z, acc[14]);
            acc[15] = fmaf(h1v, w2d.w, acc[15]);
        }
    }

    // butterfly reduce-scatter: lane g ends with sum over lanes of acc[g]
    #pragma unroll
    for (int mset = 8; mset > 0; mset >>= 1) {
        #pragma unroll
        for (int c = 0; c < 16; ++c) {
            float tmp = __shfl_xor(acc[c], mset);
            if (((c ^ g) & mset) == 0) acc[c] += tmp;
        }
    }
    float red = acc[0];
    #pragma unroll
    for (int c = 1; c < 16; ++c) red = (g == c) ? acc[c] : red;

    float fdg = (float)dg;
    float inv = 1.0f / fmaxf(fdg, 1.0f);
    float h = fmaxf((red + fdg * b2g) * inv, 0.0f);

    // logits via 16-lane allreduce
    float c0 = h * wp0, c1 = h * wp1;
    #pragma unroll
    for (int mset = 8; mset > 0; mset >>= 1) {
        c0 += __shfl_xor(c0, mset);
        c1 += __shfl_xor(c1, mset);
    }
    float l0 = c0 + bp[0], l1 = c1 + bp[1];
    float mx = fmaxf(l0, l1);
    float e0s = __expf(l0 - mx), e1s = __expf(l1 - mx);
    float isum = 1.0f / (e0s + e1s);
    float s0 = e0s * isum, s1 = e1s * isum;

    if (g == 0) ((float2*)out_s)[n] = make_float2(s0, s1);

    // fused pooling: block-level LDS reduce over the <=2 graphs this block spans
    __shared__ float lpool[2][32];
    __shared__ int sg0;
    if (t == 0) sg0 = batch[blockIdx.x * 16];
    if (t < 64) lpool[t >> 5][t & 31] = 0.0f;
    __syncthreads();

    int gid = batch[n];
    int idx = gid - sg0;
    float p0 = s0 * h, p1 = s1 * h;
    if (idx < 2) {
        atomicAdd(&lpool[idx][g], p0);
        atomicAdd(&lpool[idx][16 + g], p1);
    } else {  // pathological tiny-graph fallback
        atomicAdd(&pooled[gid * 32 + g], p0);
        atomicAdd(&pooled[gid * 32 + 16 + g], p1);
    }
    __syncthreads();
    if (t < 32) {
        float v = lpool[0][t];
        if (v != 0.0f) atomicAdd(&pooled[sg0 * 32 + t], v);
        v = lpool[1][t];
        if (v != 0.0f) atomicAdd(&pooled[(sg0 + 1) * 32 + t], v);
    }
}

// ---------------------------------------------------------------------------
// z = pooled.reshape(G,32) @ Wz + bz
// ---------------------------------------------------------------------------
__global__ __launch_bounds__(256) void z_kernel(const float* __restrict__ pooled,
                                                const float* __restrict__ Wz,
                                                const float* __restrict__ bz,
                                                float* __restrict__ out_z) {
    int idx = blockIdx.x * 256 + threadIdx.x;
    if (idx >= N_GRAPHS * 8) return;
    int gph = idx >> 3, o = idx & 7;
    float a = bz[o];
    const float* pp = pooled + (size_t)gph * 32;
    #pragma unroll
    for (int j = 0; j < 32; ++j) a = fmaf(pp[j], Wz[j * 8 + o], a);
    out_z[idx] = a;
}

extern "C" void kernel_launch(void* const* d_in, const int* in_sizes, int n_in,
                              void* d_out, int out_size, void* d_ws, size_t ws_size,
                              hipStream_t stream) {
    const float* x    = (const float*)d_in[0];
    const float* pos  = (const float*)d_in[1];
    const float* W1   = (const float*)d_in[2];
    const float* b1   = (const float*)d_in[3];
    const float* W2   = (const float*)d_in[4];
    const float* b2   = (const float*)d_in[5];
    const float* Wp   = (const float*)d_in[6];
    const float* bp   = (const float*)d_in[7];
    const float* Wz   = (const float*)d_in[8];
    const float* bz   = (const float*)d_in[9];
    const int*   ei   = (const int*)d_in[10];
    const int*   batch= (const int*)d_in[11];
    float* out = (float*)d_out;
    float* out_z = out;                   // [1024*8]
    float* out_s = out + N_GRAPHS * 8;    // [262144*2]

    // ws layout (ints): cnt[262144] offs[262144] bsum[256] boffs[256]
    //                   start[N] deg[N] pooled[1025*32]f srcs[E] binned[E]
    // px (float4[2N] = 8MB) aliases binned (16MB), written after passC.
    int* cnt    = (int*)d_ws;
    int* offs   = cnt + 262144;
    int* bsum   = offs + 262144;
    int* boffs  = bsum + 256;
    int* startg = boffs + 256;
    int* degg   = startg + N_NODES;
    float* pooled = (float*)(degg + N_NODES);
    int* srcs   = (int*)(pooled + 1025 * 32);
    int* binned = srcs + N_EDGES;
    float4* px  = (float4*)binned;

    hipMemsetAsync(pooled, 0, 1025 * 32 * sizeof(float), stream);

    passA_hist<<<256, 256, 0, stream>>>(ei, cnt);
    scan1<<<256, 256, 0, stream>>>(cnt, bsum);
    scan2<<<1, 256, 0, stream>>>(bsum, boffs);
    scan3<<<256, 256, 0, stream>>>(cnt, boffs, offs);
    passB_scatter<<<256, 256, 0, stream>>>(ei, offs, binned);
    passC_csr<<<NB, 256, 0, stream>>>(binned, offs, startg, degg, srcs);
    pack_kernel<<<N_NODES / 256, 256, 0, stream>>>(x, pos, px);
    node_gather_fused<<<N_NODES / 16, 256, 0, stream>>>(
        px, srcs, startg, degg, W1, b1, W2, b2, Wp, bp, batch, out_s, pooled);
    z_kernel<<<(N_GRAPHS * 8 + 255) / 256, 256, 0, stream>>>(pooled, Wz, bz, out_z);
}

// Round 5
// 229.081 us; speedup vs baseline: 18.4326x; 1.1917x over previous
//
#include <hip/hip_runtime.h>
#include <math.h>

#define N_NODES 262144
#define N_EDGES 4194304
#define N_GRAPHS 1024
#define NB 1024              // dst buckets (256 nodes each)
#define EPB 16384            // edges per block in passes A/B (256 blocks)

// ---------------------------------------------------------------------------
// Pass A: per-block bucket histogram -> cnt[bucket*256 + block]
// ---------------------------------------------------------------------------
__global__ __launch_bounds__(256) void passA_hist(const int* __restrict__ ei,
                                                  int* __restrict__ cnt) {
    __shared__ int lhist[NB];
    int t = threadIdx.x, b = blockIdx.x;
    #pragma unroll
    for (int k = 0; k < 4; ++k) lhist[t + 256 * k] = 0;
    __syncthreads();
    int base = b * EPB;
    for (int i = 0; i < EPB / 256; ++i) {
        int d = ei[N_EDGES + base + i * 256 + t];
        atomicAdd(&lhist[d >> 8], 1);
    }
    __syncthreads();
    #pragma unroll
    for (int k = 0; k < 4; ++k) {
        int kb = t + 256 * k;
        cnt[kb * 256 + b] = lhist[kb];
    }
}

// ---------------------------------------------------------------------------
// Exclusive scan of cnt[262144] -> offs   (3 kernels, 256x256x int4)
// ---------------------------------------------------------------------------
__global__ __launch_bounds__(256) void scan1(const int* __restrict__ v,
                                             int* __restrict__ bsum) {
    __shared__ int lsum[256];
    int b = blockIdx.x, t = threadIdx.x;
    int4 x = ((const int4*)v)[b * 256 + t];
    lsum[t] = x.x + x.y + x.z + x.w;
    __syncthreads();
    for (int o = 128; o > 0; o >>= 1) {
        if (t < o) lsum[t] += lsum[t + o];
        __syncthreads();
    }
    if (t == 0) bsum[b] = lsum[0];
}

__global__ __launch_bounds__(256) void scan2(const int* __restrict__ bsum,
                                             int* __restrict__ boffs) {
    __shared__ int tmp[256];
    int t = threadIdx.x;
    tmp[t] = bsum[t];
    __syncthreads();
    for (int o = 1; o < 256; o <<= 1) {
        int u = (t >= o) ? tmp[t - o] : 0;
        __syncthreads();
        tmp[t] += u;
        __syncthreads();
    }
    boffs[t] = tmp[t] - bsum[t];
}

__global__ __launch_bounds__(256) void scan3(const int* __restrict__ v,
                                             const int* __restrict__ boffs,
                                             int* __restrict__ offs) {
    __shared__ int tsum[256];
    int b = blockIdx.x, t = threadIdx.x;
    int4 x = ((const int4*)v)[b * 256 + t];
    int tot = x.x + x.y + x.z + x.w;
    tsum[t] = tot;
    __syncthreads();
    for (int o = 1; o < 256; o <<= 1) {
        int u = (t >= o) ? tsum[t - o] : 0;
        __syncthreads();
        tsum[t] += u;
        __syncthreads();
    }
    int base = boffs[b] + tsum[t] - tot;
    int4 p;
    p.x = base;
    p.y = p.x + x.x;
    p.z = p.y + x.y;
    p.w = p.z + x.z;
    ((int4*)offs)[b * 256 + t] = p;
}

// ---------------------------------------------------------------------------
// Pass B: scatter packed (src | dstlow<<18) into bucket-sorted order using
// per-(block,bucket) reserved ranges (LDS cursors seeded from offs).
// ---------------------------------------------------------------------------
__global__ __launch_bounds__(256) void passB_scatter(const int* __restrict__ ei,
                                                     const int* __restrict__ offs,
                                                     int* __restrict__ binned) {
    __shared__ int cur[NB];
    int t = threadIdx.x, b = blockIdx.x;
    #pragma unroll
    for (int k = 0; k < 4; ++k) {
        int kb = t + 256 * k;
        cur[kb] = offs[kb * 256 + b];
    }
    __syncthreads();
    int base = b * EPB;
    for (int i = 0; i < EPB / 256; ++i) {
        int e = base + i * 256 + t;
        int s = ei[e];
        int d = ei[N_EDGES + e];
        int slot = atomicAdd(&cur[d >> 8], 1);
        binned[slot] = s | ((d & 0xFF) << 18);
    }
}

// ---------------------------------------------------------------------------
// Pass C: per-bucket local CSR: node start/deg + srcs in final CSR order.
// ---------------------------------------------------------------------------
__global__ __launch_bounds__(256) void passC_csr(const int* __restrict__ binned,
                                                 const int* __restrict__ offs,
                                                 int* __restrict__ startg,
                                                 int* __restrict__ degg,
                                                 int* __restrict__ srcs) {
    __shared__ int ldeg[256], sc[256], lcur[256];
    int t = threadIdx.x, k = blockIdx.x;
    int ebase = offs[k * 256];
    int eend = (k == NB - 1) ? N_EDGES : offs[(k + 1) * 256];
    int ecnt = eend - ebase;

    ldeg[t] = 0;
    __syncthreads();
    for (int i = t; i < ecnt; i += 256) {
        int pk = binned[ebase + i];
        atomicAdd(&ldeg[pk >> 18], 1);
    }
    __syncthreads();
    sc[t] = ldeg[t];
    __syncthreads();
    for (int o = 1; o < 256; o <<= 1) {
        int u = (t >= o) ? sc[t - o] : 0;
        __syncthreads();
        sc[t] += u;
        __syncthreads();
    }
    int excl = sc[t] - ldeg[t];
    int n = k * 256 + t;
    startg[n] = ebase + excl;
    degg[n] = ldeg[t];
    lcur[t] = ebase + excl;
    __syncthreads();
    for (int i = t; i < ecnt; i += 256) {
        int pk = binned[ebase + i];
        int slot = atomicAdd(&lcur[pk >> 18], 1);
        srcs[slot] = pk & 0x3FFFF;
    }
}

// ---------------------------------------------------------------------------
// Pack x(4) + pos(3) into one 32B record per node: 1 cache line per gather.
// ---------------------------------------------------------------------------
__global__ __launch_bounds__(256) void pack_kernel(const float* __restrict__ x,
                                                   const float* __restrict__ pos,
                                                   float4* __restrict__ px) {
    int n = blockIdx.x * 256 + threadIdx.x;
    px[2 * n] = ((const float4*)x)[n];
    px[2 * n + 1] = make_float4(pos[3 * n], pos[3 * n + 1], pos[3 * n + 2], 0.0f);
}

// ---------------------------------------------------------------------------
// Gather + edge MLP (layer-2 hoisted out of edge loop: scatter-mean is linear
// in msg and msg is linear in h1, so agg = (sum_e h1_e)@W2 + deg*b2).
// 16 lanes per node; lane g owns W1 column g (registers). Each chunk of 16
// edges is gathered (one per lane), staged in LDS, then broadcast-read
// (b128+b32, same-address = conflict-free); lane g accumulates scalar
// sumH = sum_e h1_e[g]. One 16-wide butterfly applies W2 per node.
// Fused per-graph pooling, no h materialized.
// ---------------------------------------------------------------------------
__global__ __launch_bounds__(256) void node_gather_fused(
    const float4* __restrict__ px,
    const int* __restrict__ srcs, const int* __restrict__ startg,
    const int* __restrict__ degg,
    const float* __restrict__ W1, const float* __restrict__ b1,
    const float* __restrict__ W2, const float* __restrict__ b2,
    const float* __restrict__ Wp, const float* __restrict__ bp,
    const int* __restrict__ batch,
    float* __restrict__ out_s, float* __restrict__ pooled)
{
    // edge stage: [group][slot(+pad)] — pad row to 17 units to spread groups
    // across banks (4 groups/wave read 4 distinct rows at same slot j).
    __shared__ float4 se4[16][17];
    __shared__ float  sed[16][17];

    int t = threadIdx.x;
    int g = t & 15;
    int grp = t >> 4;
    int n = blockIdx.x * 16 + grp;

    // per-lane weights (registers)
    float w1c[9];
    #pragma unroll
    for (int i = 0; i < 9; ++i) w1c[i] = W1[i * 16 + g];
    float b1g = b1[g], b2g = b2[g];
    float4 w2a = ((const float4*)W2)[g * 4 + 0];
    float4 w2b = ((const float4*)W2)[g * 4 + 1];
    float4 w2c = ((const float4*)W2)[g * 4 + 2];
    float4 w2d = ((const float4*)W2)[g * 4 + 3];
    float wp0 = Wp[2 * g], wp1 = Wp[2 * g + 1];

    int base = startg[n];
    int dg = degg[n];

    float4 xn = px[2 * n];
    float4 pn = px[2 * n + 1];
    float pre = b1g + xn.x * w1c[0] + xn.y * w1c[1] + xn.z * w1c[2] + xn.w * w1c[3];

    float sumH = 0.0f;

    for (int k0 = 0; k0 < dg; k0 += 16) {
        int rem = dg - k0;
        int cnt = rem < 16 ? rem : 16;
        if (g < cnt) {
            int s = srcs[base + k0 + g];
            float4 a = px[2 * s];
            float4 b = px[2 * s + 1];
            float dx = b.x - pn.x, dy = b.y - pn.y, dz = b.z - pn.z;
            se4[grp][g] = a;
            sed[grp][g] = sqrtf(dx * dx + dy * dy + dz * dz);
        }
        // same-wave LDS write->read: compiler inserts lgkmcnt wait; no barrier
        for (int j = 0; j < cnt; ++j) {
            float4 e = se4[grp][j];
            float ed = sed[grp][j];
            float a = pre + e.x * w1c[4] + e.y * w1c[5] + e.z * w1c[6]
                          + e.w * w1c[7] + ed * w1c[8];
            sumH += a * __builtin_amdgcn_rcpf(1.0f + __expf(-a));  // silu
        }
    }

    // apply W2 once per node: acc[c] = sumH(g) * W2[g][c], butterfly-sum over
    // g with reduce-scatter so lane g ends holding (sumH@W2)[g].
    float acc[16];
    acc[0]  = sumH * w2a.x;  acc[1]  = sumH * w2a.y;
    acc[2]  = sumH * w2a.z;  acc[3]  = sumH * w2a.w;
    acc[4]  = sumH * w2b.x;  acc[5]  = sumH * w2b.y;
    acc[6]  = sumH * w2b.z;  acc[7]  = sumH * w2b.w;
    acc[8]  = sumH * w2c.x;  acc[9]  = sumH * w2c.y;
    acc[10] = sumH * w2c.z;  acc[11] = sumH * w2c.w;
    acc[12] = sumH * w2d.x;  acc[13] = sumH * w2d.y;
    acc[14] = sumH * w2d.z;  acc[15] = sumH * w2d.w;
    #pragma unroll
    for (int mset = 8; mset > 0; mset >>= 1) {
        #pragma unroll
        for (int c = 0; c < 16; ++c) {
            float tmp = __shfl_xor(acc[c], mset);
            if (((c ^ g) & mset) == 0) acc[c] += tmp;
        }
    }
    float red = acc[0];
    #pragma unroll
    for (int c = 1; c < 16; ++c) red = (g == c) ? acc[c] : red;

    float fdg = (float)dg;
    float inv = 1.0f / fmaxf(fdg, 1.0f);
    float h = fmaxf((red + fdg * b2g) * inv, 0.0f);

    // logits via 16-lane allreduce
    float c0 = h * wp0, c1 = h * wp1;
    #pragma unroll
    for (int mset = 8; mset > 0; mset >>= 1) {
        c0 += __shfl_xor(c0, mset);
        c1 += __shfl_xor(c1, mset);
    }
    float l0 = c0 + bp[0], l1 = c1 + bp[1];
    float mx = fmaxf(l0, l1);
    float e0s = __expf(l0 - mx), e1s = __expf(l1 - mx);
    float isum = 1.0f / (e0s + e1s);
    float s0 = e0s * isum, s1 = e1s * isum;

    if (g == 0) ((float2*)out_s)[n] = make_float2(s0, s1);

    // fused pooling: block-level LDS reduce over the <=2 graphs this block spans
    __shared__ float lpool[2][32];
    __shared__ int sg0;
    if (t == 0) sg0 = batch[blockIdx.x * 16];
    if (t < 64) lpool[t >> 5][t & 31] = 0.0f;
    __syncthreads();

    int gid = batch[n];
    int idx = gid - sg0;
    float p0 = s0 * h, p1 = s1 * h;
    if (idx < 2) {
        atomicAdd(&lpool[idx][g], p0);
        atomicAdd(&lpool[idx][16 + g], p1);
    } else {  // pathological tiny-graph fallback
        atomicAdd(&pooled[gid * 32 + g], p0);
        atomicAdd(&pooled[gid * 32 + 16 + g], p1);
    }
    __syncthreads();
    if (t < 32) {
        float v = lpool[0][t];
        if (v != 0.0f) atomicAdd(&pooled[sg0 * 32 + t], v);
        v = lpool[1][t];
        if (v != 0.0f) atomicAdd(&pooled[(sg0 + 1) * 32 + t], v);
    }
}

// ---------------------------------------------------------------------------
// z = pooled.reshape(G,32) @ Wz + bz
// ---------------------------------------------------------------------------
__global__ __launch_bounds__(256) void z_kernel(const float* __restrict__ pooled,
                                                const float* __restrict__ Wz,
                                                const float* __restrict__ bz,
                                                float* __restrict__ out_z) {
    int idx = blockIdx.x * 256 + threadIdx.x;
    if (idx >= N_GRAPHS * 8) return;
    int gph = idx >> 3, o = idx & 7;
    float a = bz[o];
    const float* pp = pooled + (size_t)gph * 32;
    #pragma unroll
    for (int j = 0; j < 32; ++j) a = fmaf(pp[j], Wz[j * 8 + o], a);
    out_z[idx] = a;
}

extern "C" void kernel_launch(void* const* d_in, const int* in_sizes, int n_in,
                              void* d_out, int out_size, void* d_ws, size_t ws_size,
                              hipStream_t stream) {
    const float* x    = (const float*)d_in[0];
    const float* pos  = (const float*)d_in[1];
    const float* W1   = (const float*)d_in[2];
    const float* b1   = (const float*)d_in[3];
    const float* W2   = (const float*)d_in[4];
    const float* b2   = (const float*)d_in[5];
    const float* Wp   = (const float*)d_in[6];
    const float* bp   = (const float*)d_in[7];
    const float* Wz   = (const float*)d_in[8];
    const float* bz   = (const float*)d_in[9];
    const int*   ei   = (const int*)d_in[10];
    const int*   batch= (const int*)d_in[11];
    float* out = (float*)d_out;
    float* out_z = out;                   // [1024*8]
    float* out_s = out + N_GRAPHS * 8;    // [262144*2]

    int* cnt    = (int*)d_ws;
    int* offs   = cnt + 262144;
    int* bsum   = offs + 262144;
    int* boffs  = bsum + 256;
    int* startg = boffs + 256;
    int* degg   = startg + N_NODES;
    float* pooled = (float*)(degg + N_NODES);
    int* srcs   = (int*)(pooled + 1025 * 32);
    int* binned = srcs + N_EDGES;
    float4* px  = (float4*)binned;   // aliases binned, written after passC

    hipMemsetAsync(pooled, 0, 1025 * 32 * sizeof(float), stream);

    passA_hist<<<256, 256, 0, stream>>>(ei, cnt);
    scan1<<<256, 256, 0, stream>>>(cnt, bsum);
    scan2<<<1, 256, 0, stream>>>(bsum, boffs);
    scan3<<<256, 256, 0, stream>>>(cnt, boffs, offs);
    passB_scatter<<<256, 256, 0, stream>>>(ei, offs, binned);
    passC_csr<<<NB, 256, 0, stream>>>(binned, offs, startg, degg, srcs);
    pack_kernel<<<N_NODES / 256, 256, 0, stream>>>(x, pos, px);
    node_gather_fused<<<N_NODES / 16, 256, 0, stream>>>(
        px, srcs, startg, degg, W1, b1, W2, b2, Wp, bp, batch, out_s, pooled);
    z_kernel<<<(N_GRAPHS * 8 + 255) / 256, 256, 0, stream>>>(pooled, Wz, bz, out_z);
}

// Round 6
// 227.508 us; speedup vs baseline: 18.5600x; 1.0069x over previous
//
#include <hip/hip_runtime.h>
#include <hip/hip_fp16.h>
#include <math.h>

#define N_NODES 262144
#define N_EDGES 4194304
#define N_GRAPHS 1024
#define NB 1024              // dst buckets (256 nodes each)
#define EPB 16384            // edges per block in passes A/B (256 blocks)

// ---------------------------------------------------------------------------
// Pass A: per-block bucket histogram -> cnt[bucket*256 + block]
// ---------------------------------------------------------------------------
__global__ __launch_bounds__(256) void passA_hist(const int* __restrict__ ei,
                                                  int* __restrict__ cnt) {
    __shared__ int lhist[NB];
    int t = threadIdx.x, b = blockIdx.x;
    #pragma unroll
    for (int k = 0; k < 4; ++k) lhist[t + 256 * k] = 0;
    __syncthreads();
    int base = b * EPB;
    for (int i = 0; i < EPB / 256; ++i) {
        int d = ei[N_EDGES + base + i * 256 + t];
        atomicAdd(&lhist[d >> 8], 1);
    }
    __syncthreads();
    #pragma unroll
    for (int k = 0; k < 4; ++k) {
        int kb = t + 256 * k;
        cnt[kb * 256 + b] = lhist[kb];
    }
}

// ---------------------------------------------------------------------------
// Exclusive scan of cnt[262144] -> offs   (3 kernels, 256x256x int4)
// ---------------------------------------------------------------------------
__global__ __launch_bounds__(256) void scan1(const int* __restrict__ v,
                                             int* __restrict__ bsum) {
    __shared__ int lsum[256];
    int b = blockIdx.x, t = threadIdx.x;
    int4 x = ((const int4*)v)[b * 256 + t];
    lsum[t] = x.x + x.y + x.z + x.w;
    __syncthreads();
    for (int o = 128; o > 0; o >>= 1) {
        if (t < o) lsum[t] += lsum[t + o];
        __syncthreads();
    }
    if (t == 0) bsum[b] = lsum[0];
}

__global__ __launch_bounds__(256) void scan2(const int* __restrict__ bsum,
                                             int* __restrict__ boffs) {
    __shared__ int tmp[256];
    int t = threadIdx.x;
    tmp[t] = bsum[t];
    __syncthreads();
    for (int o = 1; o < 256; o <<= 1) {
        int u = (t >= o) ? tmp[t - o] : 0;
        __syncthreads();
        tmp[t] += u;
        __syncthreads();
    }
    boffs[t] = tmp[t] - bsum[t];
}

__global__ __launch_bounds__(256) void scan3(const int* __restrict__ v,
                                             const int* __restrict__ boffs,
                                             int* __restrict__ offs) {
    __shared__ int tsum[256];
    int b = blockIdx.x, t = threadIdx.x;
    int4 x = ((const int4*)v)[b * 256 + t];
    int tot = x.x + x.y + x.z + x.w;
    tsum[t] = tot;
    __syncthreads();
    for (int o = 1; o < 256; o <<= 1) {
        int u = (t >= o) ? tsum[t - o] : 0;
        __syncthreads();
        tsum[t] += u;
        __syncthreads();
    }
    int base = boffs[b] + tsum[t] - tot;
    int4 p;
    p.x = base;
    p.y = p.x + x.x;
    p.z = p.y + x.y;
    p.w = p.z + x.z;
    ((int4*)offs)[b * 256 + t] = p;
}

// ---------------------------------------------------------------------------
// Pass B: scatter packed (src | dstlow<<18) into bucket-sorted order using
// per-(block,bucket) reserved ranges (LDS cursors seeded from offs).
// ---------------------------------------------------------------------------
__global__ __launch_bounds__(256) void passB_scatter(const int* __restrict__ ei,
                                                     const int* __restrict__ offs,
                                                     int* __restrict__ binned) {
    __shared__ int cur[NB];
    int t = threadIdx.x, b = blockIdx.x;
    #pragma unroll
    for (int k = 0; k < 4; ++k) {
        int kb = t + 256 * k;
        cur[kb] = offs[kb * 256 + b];
    }
    __syncthreads();
    int base = b * EPB;
    for (int i = 0; i < EPB / 256; ++i) {
        int e = base + i * 256 + t;
        int s = ei[e];
        int d = ei[N_EDGES + e];
        int slot = atomicAdd(&cur[d >> 8], 1);
        binned[slot] = s | ((d & 0xFF) << 18);
    }
}

// ---------------------------------------------------------------------------
// Pass C: per-bucket local CSR: node start/deg + srcs in final CSR order.
// ---------------------------------------------------------------------------
__global__ __launch_bounds__(256) void passC_csr(const int* __restrict__ binned,
                                                 const int* __restrict__ offs,
                                                 int* __restrict__ startg,
                                                 int* __restrict__ degg,
                                                 int* __restrict__ srcs) {
    __shared__ int ldeg[256], sc[256], lcur[256];
    int t = threadIdx.x, k = blockIdx.x;
    int ebase = offs[k * 256];
    int eend = (k == NB - 1) ? N_EDGES : offs[(k + 1) * 256];
    int ecnt = eend - ebase;

    ldeg[t] = 0;
    __syncthreads();
    for (int i = t; i < ecnt; i += 256) {
        int pk = binned[ebase + i];
        atomicAdd(&ldeg[pk >> 18], 1);
    }
    __syncthreads();
    sc[t] = ldeg[t];
    __syncthreads();
    for (int o = 1; o < 256; o <<= 1) {
        int u = (t >= o) ? sc[t - o] : 0;
        __syncthreads();
        sc[t] += u;
        __syncthreads();
    }
    int excl = sc[t] - ldeg[t];
    int n = k * 256 + t;
    startg[n] = ebase + excl;
    degg[n] = ldeg[t];
    lcur[t] = ebase + excl;
    __syncthreads();
    for (int i = t; i < ecnt; i += 256) {
        int pk = binned[ebase + i];
        int slot = atomicAdd(&lcur[pk >> 18], 1);
        srcs[slot] = pk & 0x3FFFF;
    }
}

// ---------------------------------------------------------------------------
// Pack x(4) + pos(3) into one 16B fp16 record per node: px16 = 4MB total,
// fits a per-XCD L2 -> random edge gathers become mostly L2 hits.
// ---------------------------------------------------------------------------
__global__ __launch_bounds__(256) void pack_kernel(const float* __restrict__ x,
                                                   const float* __restrict__ pos,
                                                   uint4* __restrict__ px16) {
    int n = blockIdx.x * 256 + threadIdx.x;
    float4 v = ((const float4*)x)[n];
    float p0 = pos[3 * n], p1 = pos[3 * n + 1], p2 = pos[3 * n + 2];
    __half2 h0 = __floats2half2_rn(v.x, v.y);
    __half2 h1 = __floats2half2_rn(v.z, v.w);
    __half2 h2 = __floats2half2_rn(p0, p1);
    __half2 h3 = __floats2half2_rn(p2, 0.0f);
    uint4 r;
    r.x = *(unsigned int*)&h0;
    r.y = *(unsigned int*)&h1;
    r.z = *(unsigned int*)&h2;
    r.w = *(unsigned int*)&h3;
    px16[n] = r;
}

// ---------------------------------------------------------------------------
// Gather + edge MLP (W2 hoisted out of the edge loop), software-pipelined:
// while the j-loop computes chunk k from LDS, chunk k+1's px16 loads and
// chunk k+2's srcs loads are already in flight.
// 16 lanes per node; lane g owns W1 column g in registers; lane g accumulates
// scalar sumH = sum_e h1_e[g]; one butterfly per node applies W2.
// Fused per-graph pooling.
// ---------------------------------------------------------------------------
__global__ __launch_bounds__(256) void node_gather_fused(
    const uint4* __restrict__ px16,
    const int* __restrict__ srcs, const int* __restrict__ startg,
    const int* __restrict__ degg,
    const float* __restrict__ W1, const float* __restrict__ b1,
    const float* __restrict__ W2, const float* __restrict__ b2,
    const float* __restrict__ Wp, const float* __restrict__ bp,
    const int* __restrict__ batch,
    float* __restrict__ out_s, float* __restrict__ pooled)
{
    __shared__ float4 se4[16][17];
    __shared__ float  sed[16][17];

    int t = threadIdx.x;
    int g = t & 15;
    int grp = t >> 4;
    int n = blockIdx.x * 16 + grp;

    // per-lane weights (registers)
    float w1c[9];
    #pragma unroll
    for (int i = 0; i < 9; ++i) w1c[i] = W1[i * 16 + g];
    float b1g = b1[g], b2g = b2[g];
    float4 w2a = ((const float4*)W2)[g * 4 + 0];
    float4 w2b = ((const float4*)W2)[g * 4 + 1];
    float4 w2c = ((const float4*)W2)[g * 4 + 2];
    float4 w2d = ((const float4*)W2)[g * 4 + 3];
    float wp0 = Wp[2 * g], wp1 = Wp[2 * g + 1];

    int base = startg[n];
    int dg = degg[n];

    // self record
    uint4 rn = px16[n];
    float2 f01 = __half22float2(*(__half2*)&rn.x);
    float2 f23 = __half22float2(*(__half2*)&rn.y);
    float2 f45 = __half22float2(*(__half2*)&rn.z);
    float2 f67 = __half22float2(*(__half2*)&rn.w);
    float pnx = f45.x, pny = f45.y, pnz = f67.x;
    float pre = b1g + f01.x * w1c[0] + f01.y * w1c[1] + f23.x * w1c[2] + f23.y * w1c[3];

    float sumH = 0.0f;

    // pipeline prologue
    int sC = 0;
    if (g < dg) sC = srcs[base + g];
    uint4 rC = px16[sC];                       // chunk 0 records
    int sN = sC;
    if (16 + g < dg) sN = srcs[base + 16 + g]; // chunk 1 src ids

    for (int k0 = 0; k0 < dg; k0 += 16) {
        int rem = dg - k0;
        int cnt = rem < 16 ? rem : 16;
        // stage current chunk (vmcnt waits only on rC here)
        if (g < cnt) {
            float2 e01 = __half22float2(*(__half2*)&rC.x);
            float2 e23 = __half22float2(*(__half2*)&rC.y);
            float2 e45 = __half22float2(*(__half2*)&rC.z);
            float2 e67 = __half22float2(*(__half2*)&rC.w);
            float dx = e45.x - pnx, dy = e45.y - pny, dz = e67.x - pnz;
            se4[grp][g] = make_float4(e01.x, e01.y, e23.x, e23.y);
            sed[grp][g] = sqrtf(dx * dx + dy * dy + dz * dz);
        }
        // issue next chunk's record loads + next-next src ids
        uint4 rNext = px16[sN];
        int sNN = sN;
        if (k0 + 32 + g < dg) sNN = srcs[base + k0 + 32 + g];
        // compute current chunk from LDS (broadcast reads, same-wave ordering)
        for (int j = 0; j < cnt; ++j) {
            float4 e = se4[grp][j];
            float ed = sed[grp][j];
            float a = pre + e.x * w1c[4] + e.y * w1c[5] + e.z * w1c[6]
                          + e.w * w1c[7] + ed * w1c[8];
            sumH += a * __builtin_amdgcn_rcpf(1.0f + __expf(-a));  // silu
        }
        rC = rNext;
        sN = sNN;
    }

    // apply W2 once per node; butterfly reduce-scatter leaves comp g on lane g
    float acc[16];
    acc[0]  = sumH * w2a.x;  acc[1]  = sumH * w2a.y;
    acc[2]  = sumH * w2a.z;  acc[3]  = sumH * w2a.w;
    acc[4]  = sumH * w2b.x;  acc[5]  = sumH * w2b.y;
    acc[6]  = sumH * w2b.z;  acc[7]  = sumH * w2b.w;
    acc[8]  = sumH * w2c.x;  acc[9]  = sumH * w2c.y;
    acc[10] = sumH * w2c.z;  acc[11] = sumH * w2c.w;
    acc[12] = sumH * w2d.x;  acc[13] = sumH * w2d.y;
    acc[14] = sumH * w2d.z;  acc[15] = sumH * w2d.w;
    #pragma unroll
    for (int mset = 8; mset > 0; mset >>= 1) {
        #pragma unroll
        for (int c = 0; c < 16; ++c) {
            float tmp = __shfl_xor(acc[c], mset);
            if (((c ^ g) & mset) == 0) acc[c] += tmp;
        }
    }
    float red = acc[0];
    #pragma unroll
    for (int c = 1; c < 16; ++c) red = (g == c) ? acc[c] : red;

    float fdg = (float)dg;
    float inv = 1.0f / fmaxf(fdg, 1.0f);
    float h = fmaxf((red + fdg * b2g) * inv, 0.0f);

    // logits via 16-lane allreduce
    float c0 = h * wp0, c1 = h * wp1;
    #pragma unroll
    for (int mset = 8; mset > 0; mset >>= 1) {
        c0 += __shfl_xor(c0, mset);
        c1 += __shfl_xor(c1, mset);
    }
    float l0 = c0 + bp[0], l1 = c1 + bp[1];
    float mx = fmaxf(l0, l1);
    float e0s = __expf(l0 - mx), e1s = __expf(l1 - mx);
    float isum = 1.0f / (e0s + e1s);
    float s0 = e0s * isum, s1 = e1s * isum;

    if (g == 0) ((float2*)out_s)[n] = make_float2(s0, s1);

    // fused pooling: block-level LDS reduce over the <=2 graphs this block spans
    __shared__ float lpool[2][32];
    __shared__ int sg0;
    if (t == 0) sg0 = batch[blockIdx.x * 16];
    if (t < 64) lpool[t >> 5][t & 31] = 0.0f;
    __syncthreads();

    int gid = batch[n];
    int idx = gid - sg0;
    float p0 = s0 * h, p1 = s1 * h;
    if (idx < 2) {
        atomicAdd(&lpool[idx][g], p0);
        atomicAdd(&lpool[idx][16 + g], p1);
    } else {  // pathological tiny-graph fallback
        atomicAdd(&pooled[gid * 32 + g], p0);
        atomicAdd(&pooled[gid * 32 + 16 + g], p1);
    }
    __syncthreads();
    if (t < 32) {
        float v = lpool[0][t];
        if (v != 0.0f) atomicAdd(&pooled[sg0 * 32 + t], v);
        v = lpool[1][t];
        if (v != 0.0f) atomicAdd(&pooled[(sg0 + 1) * 32 + t], v);
    }
}

// ---------------------------------------------------------------------------
// z = pooled.reshape(G,32) @ Wz + bz
// ---------------------------------------------------------------------------
__global__ __launch_bounds__(256) void z_kernel(const float* __restrict__ pooled,
                                                const float* __restrict__ Wz,
                                                const float* __restrict__ bz,
                                                float* __restrict__ out_z) {
    int idx = blockIdx.x * 256 + threadIdx.x;
    if (idx >= N_GRAPHS * 8) return;
    int gph = idx >> 3, o = idx & 7;
    float a = bz[o];
    const float* pp = pooled + (size_t)gph * 32;
    #pragma unroll
    for (int j = 0; j < 32; ++j) a = fmaf(pp[j], Wz[j * 8 + o], a);
    out_z[idx] = a;
}

extern "C" void kernel_launch(void* const* d_in, const int* in_sizes, int n_in,
                              void* d_out, int out_size, void* d_ws, size_t ws_size,
                              hipStream_t stream) {
    const float* x    = (const float*)d_in[0];
    const float* pos  = (const float*)d_in[1];
    const float* W1   = (const float*)d_in[2];
    const float* b1   = (const float*)d_in[3];
    const float* W2   = (const float*)d_in[4];
    const float* b2   = (const float*)d_in[5];
    const float* Wp   = (const float*)d_in[6];
    const float* bp   = (const float*)d_in[7];
    const float* Wz   = (const float*)d_in[8];
    const float* bz   = (const float*)d_in[9];
    const int*   ei   = (const int*)d_in[10];
    const int*   batch= (const int*)d_in[11];
    float* out = (float*)d_out;
    float* out_z = out;                   // [1024*8]
    float* out_s = out + N_GRAPHS * 8;    // [262144*2]

    int* cnt    = (int*)d_ws;
    int* offs   = cnt + 262144;
    int* bsum   = offs + 262144;
    int* boffs  = bsum + 256;
    int* startg = boffs + 256;
    int* degg   = startg + N_NODES;
    float* pooled = (float*)(degg + N_NODES);
    int* srcs   = (int*)(pooled + 1025 * 32);
    int* binned = srcs + N_EDGES;
    uint4* px16 = (uint4*)binned;   // 4MB, aliases binned; written after passC

    hipMemsetAsync(pooled, 0, 1025 * 32 * sizeof(float), stream);

    passA_hist<<<256, 256, 0, stream>>>(ei, cnt);
    scan1<<<256, 256, 0, stream>>>(cnt, bsum);
    scan2<<<1, 256, 0, stream>>>(bsum, boffs);
    scan3<<<256, 256, 0, stream>>>(cnt, boffs, offs);
    passB_scatter<<<256, 256, 0, stream>>>(ei, offs, binned);
    passC_csr<<<NB, 256, 0, stream>>>(binned, offs, startg, degg, srcs);
    pack_kernel<<<N_NODES / 256, 256, 0, stream>>>(x, pos, px16);
    node_gather_fused<<<N_NODES / 16, 256, 0, stream>>>(
        px16, srcs, startg, degg, W1, b1, W2, b2, Wp, bp, batch, out_s, pooled);
    z_kernel<<<(N_GRAPHS * 8 + 255) / 256, 256, 0, stream>>>(pooled, Wz, bz, out_z);
}

// Round 7
// 188.280 us; speedup vs baseline: 22.4270x; 1.2084x over previous
//
#include <hip/hip_runtime.h>
#include <hip/hip_fp16.h>
#include <math.h>

#define N_NODES 262144
#define N_EDGES 4194304
#define N_GRAPHS 1024
#define NB 1024              // dst buckets (256 nodes each)
#define EPB 16384            // edges per block in passes A/B (256 blocks)

typedef _Float16 half2v __attribute__((ext_vector_type(2)));

__device__ inline half2v u2h(unsigned int u) {
    union { unsigned int u; half2v h; } c; c.u = u; return c.h;
}

// ---------------------------------------------------------------------------
// Pass A: per-block bucket histogram -> cnt[bucket*256 + block]
// ---------------------------------------------------------------------------
__global__ __launch_bounds__(256) void passA_hist(const int* __restrict__ ei,
                                                  int* __restrict__ cnt) {
    __shared__ int lhist[NB];
    int t = threadIdx.x, b = blockIdx.x;
    #pragma unroll
    for (int k = 0; k < 4; ++k) lhist[t + 256 * k] = 0;
    __syncthreads();
    int base = b * EPB;
    for (int i = 0; i < EPB / 256; ++i) {
        int d = ei[N_EDGES + base + i * 256 + t];
        atomicAdd(&lhist[d >> 8], 1);
    }
    __syncthreads();
    #pragma unroll
    for (int k = 0; k < 4; ++k) {
        int kb = t + 256 * k;
        cnt[kb * 256 + b] = lhist[kb];
    }
}

// ---------------------------------------------------------------------------
// Exclusive scan of cnt[262144] -> offs   (3 kernels, 256x256x int4)
// ---------------------------------------------------------------------------
__global__ __launch_bounds__(256) void scan1(const int* __restrict__ v,
                                             int* __restrict__ bsum) {
    __shared__ int lsum[256];
    int b = blockIdx.x, t = threadIdx.x;
    int4 x = ((const int4*)v)[b * 256 + t];
    lsum[t] = x.x + x.y + x.z + x.w;
    __syncthreads();
    for (int o = 128; o > 0; o >>= 1) {
        if (t < o) lsum[t] += lsum[t + o];
        __syncthreads();
    }
    if (t == 0) bsum[b] = lsum[0];
}

__global__ __launch_bounds__(256) void scan2(const int* __restrict__ bsum,
                                             int* __restrict__ boffs) {
    __shared__ int tmp[256];
    int t = threadIdx.x;
    tmp[t] = bsum[t];
    __syncthreads();
    for (int o = 1; o < 256; o <<= 1) {
        int u = (t >= o) ? tmp[t - o] : 0;
        __syncthreads();
        tmp[t] += u;
        __syncthreads();
    }
    boffs[t] = tmp[t] - bsum[t];
}

__global__ __launch_bounds__(256) void scan3(const int* __restrict__ v,
                                             const int* __restrict__ boffs,
                                             int* __restrict__ offs) {
    __shared__ int tsum[256];
    int b = blockIdx.x, t = threadIdx.x;
    int4 x = ((const int4*)v)[b * 256 + t];
    int tot = x.x + x.y + x.z + x.w;
    tsum[t] = tot;
    __syncthreads();
    for (int o = 1; o < 256; o <<= 1) {
        int u = (t >= o) ? tsum[t - o] : 0;
        __syncthreads();
        tsum[t] += u;
        __syncthreads();
    }
    int base = boffs[b] + tsum[t] - tot;
    int4 p;
    p.x = base;
    p.y = p.x + x.x;
    p.z = p.y + x.y;
    p.w = p.z + x.z;
    ((int4*)offs)[b * 256 + t] = p;
}

// ---------------------------------------------------------------------------
// Pass B: scatter packed (src | dstlow<<18) into bucket-sorted order.
// Also zeroes the pooled accumulator (dropped the separate memset dispatch).
// ---------------------------------------------------------------------------
__global__ __launch_bounds__(256) void passB_scatter(const int* __restrict__ ei,
                                                     const int* __restrict__ offs,
                                                     int* __restrict__ binned,
                                                     float* __restrict__ pooled) {
    __shared__ int cur[NB];
    int t = threadIdx.x, b = blockIdx.x;
    int pid = b * 256 + t;
    if (pid < 1025 * 32) pooled[pid] = 0.0f;
    #pragma unroll
    for (int k = 0; k < 4; ++k) {
        int kb = t + 256 * k;
        cur[kb] = offs[kb * 256 + b];
    }
    __syncthreads();
    int base = b * EPB;
    for (int i = 0; i < EPB / 256; ++i) {
        int e = base + i * 256 + t;
        int s = ei[e];
        int d = ei[N_EDGES + e];
        int slot = atomicAdd(&cur[d >> 8], 1);
        binned[slot] = s | ((d & 0xFF) << 18);
    }
}

// ---------------------------------------------------------------------------
// Pass C: per-bucket local CSR: node start/deg + srcs in final CSR order.
// ---------------------------------------------------------------------------
__global__ __launch_bounds__(256) void passC_csr(const int* __restrict__ binned,
                                                 const int* __restrict__ offs,
                                                 int* __restrict__ startg,
                                                 int* __restrict__ degg,
                                                 int* __restrict__ srcs) {
    __shared__ int ldeg[256], sc[256], lcur[256];
    int t = threadIdx.x, k = blockIdx.x;
    int ebase = offs[k * 256];
    int eend = (k == NB - 1) ? N_EDGES : offs[(k + 1) * 256];
    int ecnt = eend - ebase;

    ldeg[t] = 0;
    __syncthreads();
    for (int i = t; i < ecnt; i += 256) {
        int pk = binned[ebase + i];
        atomicAdd(&ldeg[pk >> 18], 1);
    }
    __syncthreads();
    sc[t] = ldeg[t];
    __syncthreads();
    for (int o = 1; o < 256; o <<= 1) {
        int u = (t >= o) ? sc[t - o] : 0;
        __syncthreads();
        sc[t] += u;
        __syncthreads();
    }
    int excl = sc[t] - ldeg[t];
    int n = k * 256 + t;
    startg[n] = ebase + excl;
    degg[n] = ldeg[t];
    lcur[t] = ebase + excl;
    __syncthreads();
    for (int i = t; i < ecnt; i += 256) {
        int pk = binned[ebase + i];
        int slot = atomicAdd(&lcur[pk >> 18], 1);
        srcs[slot] = pk & 0x3FFFF;
    }
}

// ---------------------------------------------------------------------------
// Pack x(4) + pos(3) into one 16B fp16 record per node (px16 = 4MB, L2-fits).
// ---------------------------------------------------------------------------
__global__ __launch_bounds__(256) void pack_kernel(const float* __restrict__ x,
                                                   const float* __restrict__ pos,
                                                   uint4* __restrict__ px16) {
    int n = blockIdx.x * 256 + threadIdx.x;
    float4 v = ((const float4*)x)[n];
    float p0 = pos[3 * n], p1 = pos[3 * n + 1], p2 = pos[3 * n + 2];
    __half2 h0 = __floats2half2_rn(v.x, v.y);
    __half2 h1 = __floats2half2_rn(v.z, v.w);
    __half2 h2 = __floats2half2_rn(p0, p1);
    __half2 h3 = __floats2half2_rn(p2, 0.0f);
    uint4 r;
    r.x = *(unsigned int*)&h0;
    r.y = *(unsigned int*)&h1;
    r.z = *(unsigned int*)&h2;
    r.w = *(unsigned int*)&h3;
    px16[n] = r;
}

// ---------------------------------------------------------------------------
// Gather + edge MLP. Inner loop: 1 ds_read_b128/edge (x packed fp16 + dist
// f32) + 2 v_dot2_f32_f16 + exp chain (~8 VALU). W2 applied once per node via
// LDS transpose of sumH (replaces the 64-bpermute butterfly). Fused pooling.
// ---------------------------------------------------------------------------
__global__ __launch_bounds__(256) void node_gather_fused(
    const uint4* __restrict__ px16,
    const int* __restrict__ srcs, const int* __restrict__ startg,
    const int* __restrict__ degg,
    const float* __restrict__ W1, const float* __restrict__ b1,
    const float* __restrict__ W2, const float* __restrict__ b2,
    const float* __restrict__ Wp, const float* __restrict__ bp,
    const int* __restrict__ batch,
    float* __restrict__ out_s, float* __restrict__ pooled)
{
    __shared__ uint4 sepk[16][17];   // staged edges: {x01,x23,dist,pad}
    __shared__ float smh[16][20];    // sumH transpose (padded rows)

    int t = threadIdx.x;
    int g = t & 15;
    int grp = t >> 4;
    int n = blockIdx.x * 16 + grp;

    // per-lane weights (registers)
    float w1c0 = W1[0 * 16 + g], w1c1 = W1[1 * 16 + g];
    float w1c2 = W1[2 * 16 + g], w1c3 = W1[3 * 16 + g];
    half2v wh45, wh67;
    wh45[0] = (_Float16)W1[4 * 16 + g];
    wh45[1] = (_Float16)W1[5 * 16 + g];
    wh67[0] = (_Float16)W1[6 * 16 + g];
    wh67[1] = (_Float16)W1[7 * 16 + g];
    float w1c8 = W1[8 * 16 + g];
    float b1g = b1[g], b2g = b2[g];
    float w2col[16];
    #pragma unroll
    for (int i = 0; i < 16; ++i) w2col[i] = W2[i * 16 + g];  // column g
    float wp0 = Wp[2 * g], wp1 = Wp[2 * g + 1];

    int base = startg[n];
    int dg = degg[n];

    // self record
    uint4 rn = px16[n];
    float2 f01 = __half22float2(*(__half2*)&rn.x);
    float2 f23 = __half22float2(*(__half2*)&rn.y);
    float2 f45 = __half22float2(*(__half2*)&rn.z);
    float2 f67 = __half22float2(*(__half2*)&rn.w);
    float pnx = f45.x, pny = f45.y, pnz = f67.x;
    float pre = b1g + f01.x * w1c0 + f01.y * w1c1 + f23.x * w1c2 + f23.y * w1c3;

    float sumH = 0.0f;

    // pipeline prologue
    int sC = 0;
    if (g < dg) sC = srcs[base + g];
    uint4 rC = px16[sC];
    int sN = sC;
    if (16 + g < dg) sN = srcs[base + 16 + g];

    for (int k0 = 0; k0 < dg; k0 += 16) {
        int rem = dg - k0;
        int cnt = rem < 16 ? rem : 16;
        if (g < cnt) {
            float2 e45 = __half22float2(*(__half2*)&rC.z);
            float2 e67 = __half22float2(*(__half2*)&rC.w);
            float dx = e45.x - pnx, dy = e45.y - pny, dz = e67.x - pnz;
            float dist = sqrtf(dx * dx + dy * dy + dz * dz);
            sepk[grp][g] = make_uint4(rC.x, rC.y, __float_as_uint(dist), 0u);
        }
        // issue next chunk's loads
        uint4 rNext = px16[sN];
        int sNN = sN;
        if (k0 + 32 + g < dg) sNN = srcs[base + k0 + 32 + g];
        // compute current chunk from LDS (2x unrolled to batch waits)
        int j = 0;
        for (; j + 1 < cnt; j += 2) {
            uint4 A = sepk[grp][j];
            uint4 B = sepk[grp][j + 1];
            float a = fmaf(__uint_as_float(A.z), w1c8, pre);
            a = __builtin_amdgcn_fdot2(u2h(A.x), wh45, a, false);
            a = __builtin_amdgcn_fdot2(u2h(A.y), wh67, a, false);
            sumH += a * __builtin_amdgcn_rcpf(1.0f + __expf(-a));
            float b = fmaf(__uint_as_float(B.z), w1c8, pre);
            b = __builtin_amdgcn_fdot2(u2h(B.x), wh45, b, false);
            b = __builtin_amdgcn_fdot2(u2h(B.y), wh67, b, false);
            sumH += b * __builtin_amdgcn_rcpf(1.0f + __expf(-b));
        }
        if (j < cnt) {
            uint4 A = sepk[grp][j];
            float a = fmaf(__uint_as_float(A.z), w1c8, pre);
            a = __builtin_amdgcn_fdot2(u2h(A.x), wh45, a, false);
            a = __builtin_amdgcn_fdot2(u2h(A.y), wh67, a, false);
            sumH += a * __builtin_amdgcn_rcpf(1.0f + __expf(-a));
        }
        rC = rNext;
        sN = sNN;
    }

    // LDS-transpose epilogue: lane g applies W2 column g.
    // Same-wave DS ops are in-order: write then read needs no barrier.
    smh[grp][g] = sumH;
    float4 s0v = *(const float4*)&smh[grp][0];
    float4 s1v = *(const float4*)&smh[grp][4];
    float4 s2v = *(const float4*)&smh[grp][8];
    float4 s3v = *(const float4*)&smh[grp][12];
    float red = s0v.x * w2col[0] + s0v.y * w2col[1] + s0v.z * w2col[2] + s0v.w * w2col[3]
              + s1v.x * w2col[4] + s1v.y * w2col[5] + s1v.z * w2col[6] + s1v.w * w2col[7]
              + s2v.x * w2col[8] + s2v.y * w2col[9] + s2v.z * w2col[10] + s2v.w * w2col[11]
              + s3v.x * w2col[12] + s3v.y * w2col[13] + s3v.z * w2col[14] + s3v.w * w2col[15];

    float fdg = (float)dg;
    float inv = 1.0f / fmaxf(fdg, 1.0f);
    float h = fmaxf((red + fdg * b2g) * inv, 0.0f);

    // logits via 16-lane allreduce
    float c0 = h * wp0, c1 = h * wp1;
    #pragma unroll
    for (int mset = 8; mset > 0; mset >>= 1) {
        c0 += __shfl_xor(c0, mset);
        c1 += __shfl_xor(c1, mset);
    }
    float l0 = c0 + bp[0], l1 = c1 + bp[1];
    float mx = fmaxf(l0, l1);
    float e0s = __expf(l0 - mx), e1s = __expf(l1 - mx);
    float isum = 1.0f / (e0s + e1s);
    float s0 = e0s * isum, s1 = e1s * isum;

    if (g == 0) ((float2*)out_s)[n] = make_float2(s0, s1);

    // fused pooling: block-level LDS reduce over the <=2 graphs this block spans
    __shared__ float lpool[2][32];
    __shared__ int sg0;
    if (t == 0) sg0 = batch[blockIdx.x * 16];
    if (t < 64) lpool[t >> 5][t & 31] = 0.0f;
    __syncthreads();

    int gid = batch[n];
    int idx = gid - sg0;
    float p0 = s0 * h, p1 = s1 * h;
    if (idx < 2) {
        atomicAdd(&lpool[idx][g], p0);
        atomicAdd(&lpool[idx][16 + g], p1);
    } else {  // pathological tiny-graph fallback
        atomicAdd(&pooled[gid * 32 + g], p0);
        atomicAdd(&pooled[gid * 32 + 16 + g], p1);
    }
    __syncthreads();
    if (t < 32) {
        float v = lpool[0][t];
        if (v != 0.0f) atomicAdd(&pooled[sg0 * 32 + t], v);
        v = lpool[1][t];
        if (v != 0.0f) atomicAdd(&pooled[(sg0 + 1) * 32 + t], v);
    }
}

// ---------------------------------------------------------------------------
// z = pooled.reshape(G,32) @ Wz + bz
// ---------------------------------------------------------------------------
__global__ __launch_bounds__(256) void z_kernel(const float* __restrict__ pooled,
                                                const float* __restrict__ Wz,
                                                const float* __restrict__ bz,
                                                float* __restrict__ out_z) {
    int idx = blockIdx.x * 256 + threadIdx.x;
    if (idx >= N_GRAPHS * 8) return;
    int gph = idx >> 3, o = idx & 7;
    float a = bz[o];
    const float* pp = pooled + (size_t)gph * 32;
    #pragma unroll
    for (int j = 0; j < 32; ++j) a = fmaf(pp[j], Wz[j * 8 + o], a);
    out_z[idx] = a;
}

extern "C" void kernel_launch(void* const* d_in, const int* in_sizes, int n_in,
                              void* d_out, int out_size, void* d_ws, size_t ws_size,
                              hipStream_t stream) {
    const float* x    = (const float*)d_in[0];
    const float* pos  = (const float*)d_in[1];
    const float* W1   = (const float*)d_in[2];
    const float* b1   = (const float*)d_in[3];
    const float* W2   = (const float*)d_in[4];
    const float* b2   = (const float*)d_in[5];
    const float* Wp   = (const float*)d_in[6];
    const float* bp   = (const float*)d_in[7];
    const float* Wz   = (const float*)d_in[8];
    const float* bz   = (const float*)d_in[9];
    const int*   ei   = (const int*)d_in[10];
    const int*   batch= (const int*)d_in[11];
    float* out = (float*)d_out;
    float* out_z = out;                   // [1024*8]
    float* out_s = out + N_GRAPHS * 8;    // [262144*2]

    int* cnt    = (int*)d_ws;
    int* offs   = cnt + 262144;
    int* bsum   = offs + 262144;
    int* boffs  = bsum + 256;
    int* startg = boffs + 256;
    int* degg   = startg + N_NODES;
    float* pooled = (float*)(degg + N_NODES);
    int* srcs   = (int*)(pooled + 1025 * 32);
    int* binned = srcs + N_EDGES;
    uint4* px16 = (uint4*)binned;   // 4MB, aliases binned; written after passC

    passA_hist<<<256, 256, 0, stream>>>(ei, cnt);
    scan1<<<256, 256, 0, stream>>>(cnt, bsum);
    scan2<<<1, 256, 0, stream>>>(bsum, boffs);
    scan3<<<256, 256, 0, stream>>>(cnt, boffs, offs);
    passB_scatter<<<256, 256, 0, stream>>>(ei, offs, binned, pooled);
    passC_csr<<<NB, 256, 0, stream>>>(binned, offs, startg, degg, srcs);
    pack_kernel<<<N_NODES / 256, 256, 0, stream>>>(x, pos, px16);
    node_gather_fused<<<N_NODES / 16, 256, 0, stream>>>(
        px16, srcs, startg, degg, W1, b1, W2, b2, Wp, bp, batch, out_s, pooled);
    z_kernel<<<(N_GRAPHS * 8 + 255) / 256, 256, 0, stream>>>(pooled, Wz, bz, out_z);
}